// Round 1
// baseline (351.897 us; speedup 1.0000x reference)
//
#include <hip/hip_runtime.h>

// OnlineReweightingLoss: N=1048576, C=64, S=8.
// out = sum_k ( sum_{i in key k} per_sample_i ) / count_k
//
// Kernel A: 512 blocks x 512 thr (R1: was 256 thr; 2 blocks/CU -> 16 waves/CU
//   = 4 waves/SIMD, doubling latency hiding for the nontemporal load chain).
//   16 lanes/row (lane owns one float4), 16 rows/wave-iter; lane's 4 rows are
//   CONTIGUOUS (row = base+4g+j) so targets/subg load as one int4 each (2 VMEM
//   instrs vs 8). Logits via 4 independent nontemporal dwordx4 loads (16 lines
//   each, fully coalesced). Row-sum via shfl_xor(16); owner lane -> 512-bin
//   LDS histogram; flush = plain coalesced stores to private per-block slice
//   (no global atomics).
// Kernel B: 64 blocks x 256 thr; block b reduces keys [8b,8b+8) across all
//   512 slices (L2-resident), one atomicAdd(out) per block (64 total).

#define NKEYS 512
#define NSLICES 512   // == kernel A grid size
#define ABLOCK 512    // kernel A block size (8 waves)
typedef float v4f __attribute__((ext_vector_type(4)));

__device__ __forceinline__ float pick4(v4f v, int j) {
    float r = v.x;
    r = (j == 1) ? v.y : r;
    r = (j == 2) ? v.z : r;
    r = (j == 3) ? v.w : r;
    return r;
}

__device__ __forceinline__ float esum4(v4f v) {
    return __expf(v.x) + __expf(v.y) + __expf(v.z) + __expf(v.w);
}

__global__ __launch_bounds__(ABLOCK, 4)
void orl_hist_kernel(const float* __restrict__ logits,
                     const int* __restrict__ targets,
                     const int* __restrict__ subg,
                     float* __restrict__ psum,          // [NSLICES][NKEYS]
                     unsigned int* __restrict__ pcnt,   // [NSLICES][NKEYS]
                     int n) {
    __shared__ float        lsum[NKEYS];
    __shared__ unsigned int lcnt[NKEYS];
    for (int i = threadIdx.x; i < NKEYS; i += ABLOCK) { lsum[i] = 0.0f; lcnt[i] = 0u; }
    __syncthreads();

    const int lane = threadIdx.x & 63;
    const int q    = lane & 15;        // float4 index within row
    const int g    = lane >> 4;        // 4-row group within wave's 16 rows
    const int wave = (blockIdx.x << 3) | (threadIdx.x >> 6);   // 8 waves/block
    const int nwaves = gridDim.x << 3;

    int base = wave * 16;
    for (; base + 16 <= n; base += nwaves * 16) {
        const int r0 = base + g * 4;   // this lane-group's 4 contiguous rows
        // one int4 each for 4 targets / 4 subgroups (was 8 scalar loads)
        const int4 t4 = *(const int4*)(targets + r0);
        const int4 u4 = *(const int4*)(subg + r0);
        // 4 independent dwordx4 loads, 64-B-line coalesced; nontemporal.
        const float* rowp = logits + (size_t)r0 * 64 + q * 4;
        const v4f v0 = __builtin_nontemporal_load((const v4f*)(rowp));
        const v4f v1 = __builtin_nontemporal_load((const v4f*)(rowp + 64));
        const v4f v2 = __builtin_nontemporal_load((const v4f*)(rowp + 128));
        const v4f v3 = __builtin_nontemporal_load((const v4f*)(rowp + 192));

        float s0 = esum4(v0), s1 = esum4(v1), s2 = esum4(v2), s3 = esum4(v3);
        // xor-reduce over the 16 q-lanes sharing each row
        #pragma unroll
        for (int m = 1; m < 16; m <<= 1) {
            s0 += __shfl_xor(s0, m, 16);
            s1 += __shfl_xor(s1, m, 16);
            s2 += __shfl_xor(s2, m, 16);
            s3 += __shfl_xor(s3, m, 16);
        }
        if ((t4.x >> 2) == q) {
            const float ps = __logf(s0) - pick4(v0, t4.x & 3);
            atomicAdd(&lsum[t4.x * 8 + u4.x], ps); atomicAdd(&lcnt[t4.x * 8 + u4.x], 1u);
        }
        if ((t4.y >> 2) == q) {
            const float ps = __logf(s1) - pick4(v1, t4.y & 3);
            atomicAdd(&lsum[t4.y * 8 + u4.y], ps); atomicAdd(&lcnt[t4.y * 8 + u4.y], 1u);
        }
        if ((t4.z >> 2) == q) {
            const float ps = __logf(s2) - pick4(v2, t4.z & 3);
            atomicAdd(&lsum[t4.z * 8 + u4.z], ps); atomicAdd(&lcnt[t4.z * 8 + u4.z], 1u);
        }
        if ((t4.w >> 2) == q) {
            const float ps = __logf(s3) - pick4(v3, t4.w & 3);
            atomicAdd(&lsum[t4.w * 8 + u4.w], ps); atomicAdd(&lcnt[t4.w * 8 + u4.w], 1u);
        }
    }
    // generic-n tail (not taken for N=1M with this grid)
    for (int o = 0; o < 4; ++o) {
        const int r = base + g * 4 + o;
        if (r < n) {
            const v4f v = *((const v4f*)(logits + (size_t)r * 64) + q);
            const int t = targets[r];
            float s = esum4(v);
            #pragma unroll
            for (int m = 1; m < 16; m <<= 1) s += __shfl_xor(s, m, 16);
            if ((t >> 2) == q) {
                const float ps = __logf(s) - pick4(v, t & 3);
                const int key = t * 8 + subg[r];
                atomicAdd(&lsum[key], ps); atomicAdd(&lcnt[key], 1u);
            }
        }
    }

    __syncthreads();
    // Private-slice flush: plain coalesced stores, all 512 bins.
    const size_t sbase = (size_t)blockIdx.x * NKEYS;
    for (int i = threadIdx.x; i < NKEYS; i += ABLOCK) {
        psum[sbase + i] = lsum[i];
        pcnt[sbase + i] = lcnt[i];
    }
}

__global__ __launch_bounds__(256)
void orl_reduce_kernel(const float* __restrict__ psum,
                       const unsigned int* __restrict__ pcnt,
                       float* __restrict__ out) {
    const int kk  = threadIdx.x & 7;          // key within this block's 8
    const int sl  = threadIdx.x >> 3;         // 32 slice-lanes
    const int key = (blockIdx.x << 3) | kk;
    float s = 0.0f; unsigned int c = 0u;
    #pragma unroll 4
    for (int b = sl; b < NSLICES; b += 32) {
        s += psum[(size_t)b * NKEYS + key];
        c += pcnt[(size_t)b * NKEYS + key];
    }
    // reduce over lanes with the same kk inside the wave (xor 8,16,32)
    #pragma unroll
    for (int m = 8; m < 64; m <<= 1) {
        s += __shfl_xor(s, m, 64);
        c += __shfl_xor(c, m, 64);
    }
    __shared__ float        ls[4][8];
    __shared__ unsigned int lc[4][8];
    const int w = threadIdx.x >> 6;
    if ((threadIdx.x & 63) < 8) { ls[w][kk] = s; lc[w][kk] = c; }
    __syncthreads();
    if (threadIdx.x < 8) {
        const float        S = ls[0][kk] + ls[1][kk] + ls[2][kk] + ls[3][kk];
        const unsigned int C = lc[0][kk] + lc[1][kk] + lc[2][kk] + lc[3][kk];
        float v = C ? S / (float)C : 0.0f;
        #pragma unroll
        for (int m = 1; m < 8; m <<= 1) v += __shfl_xor(v, m, 8);
        if (threadIdx.x == 0) atomicAdd(out, v);   // 64 uncontended adds
    }
}

extern "C" void kernel_launch(void* const* d_in, const int* in_sizes, int n_in,
                              void* d_out, int out_size, void* d_ws, size_t ws_size,
                              hipStream_t stream) {
    const float* logits  = (const float*)d_in[0];
    const int*   targets = (const int*)d_in[1];
    const int*   subg    = (const int*)d_in[2];
    const int n = in_sizes[1];
    float* out = (float*)d_out;

    float*        psum = (float*)d_ws;                            // 1 MB
    unsigned int* pcnt = (unsigned int*)((char*)d_ws + (size_t)NSLICES * NKEYS * 4);

    hipMemsetAsync(out, 0, sizeof(float), stream);  // atomic target
    orl_hist_kernel<<<NSLICES, ABLOCK, 0, stream>>>(logits, targets, subg, psum, pcnt, n);
    orl_reduce_kernel<<<64, 256, 0, stream>>>(psum, pcnt, out);
}